// Round 2
// baseline (3992.377 us; speedup 1.0000x reference)
//
#include <hip/hip_runtime.h>
#include <stdint.h>

typedef unsigned int u32;
typedef unsigned long long u64;

// ---------------------------------------------------------------------------
// Threefry-2x32, 20 rounds — bit-exact replica of JAX's threefry2x32 primitive.
// ---------------------------------------------------------------------------
__host__ __device__ __forceinline__ void tf2x32(u32 k0, u32 k1, u32 x0, u32 x1,
                                                u32& o0, u32& o1) {
  u32 k2 = k0 ^ k1 ^ 0x1BD11BDAu;
  x0 += k0; x1 += k1;
#define TFR(r) { x0 += x1; x1 = (x1 << (r)) | (x1 >> (32 - (r))); x1 ^= x0; }
  TFR(13) TFR(15) TFR(26) TFR(6)   x0 += k1; x1 += k2 + 1u;
  TFR(17) TFR(29) TFR(16) TFR(24)  x0 += k2; x1 += k0 + 2u;
  TFR(13) TFR(15) TFR(26) TFR(6)   x0 += k0; x1 += k1 + 3u;
  TFR(17) TFR(29) TFR(16) TFR(24)  x0 += k1; x1 += k2 + 4u;
  TFR(13) TFR(15) TFR(26) TFR(6)   x0 += k2; x1 += k0 + 5u;
#undef TFR
  o0 = x0; o1 = x1;
}

// stoch_act: p = clip((y+1)*0.5, 0, 1); u built from partitionable random bits
// of flat index j: bits = o0 ^ o1 of TF(key, (0, j))  [jax _threefry_random_bits
// _partitionable, 32-bit path]. Returns true if output = -1.
__device__ __forceinline__ bool act_neg(float y, u32 k0, u32 k1, u32 j) {
  u32 o0, o1;
  tf2x32(k0, k1, 0u, j, o0, o1);
  u32 bits = o0 ^ o1;
  float u = __uint_as_float(0x3f800000u | (bits >> 9)) - 1.0f;
  float t = (y + 1.0f) * 0.5f;
  float p = fminf(fmaxf(t, 0.0f), 1.0f);
  return !(u < p);
}

// ---------------------------------------------------------------------------
// Weight packing: bit = 1 iff weight < 0 (value -1). Conv: [C][Cin][3][3] ->
// [C][9][Cin/32]. FC: [O][K] -> [O][K/32].
// ---------------------------------------------------------------------------
__global__ void k_pack_convw(const float* __restrict__ w, u32* __restrict__ pw,
                             int Cout, int Cin) {
  int Wi = Cin >> 5;
  int idx = blockIdx.x * blockDim.x + threadIdx.x;
  int total = Cout * 9 * Wi;
  if (idx >= total) return;
  int wi = idx % Wi;
  int t = (idx / Wi) % 9;
  int co = idx / (Wi * 9);
  int kh = t / 3, kw = t % 3;
  u32 word = 0;
  for (int b = 0; b < 32; ++b) {
    int ci = wi * 32 + b;
    float v = w[((co * Cin + ci) * 3 + kh) * 3 + kw];
    word |= (v < 0.0f ? 1u : 0u) << b;
  }
  pw[idx] = word;
}

__global__ void k_pack_fcw(const float* __restrict__ w, u32* __restrict__ pw,
                           int O, int K) {
  int KW = K >> 5;
  int idx = blockIdx.x * blockDim.x + threadIdx.x;
  if (idx >= O * KW) return;
  int kw = idx % KW, o = idx / KW;
  u32 word = 0;
  for (int b = 0; b < 32; ++b)
    word |= (w[o * K + kw * 32 + b] < 0.0f ? 1u : 0u) << b;
  pw[idx] = word;
}

// ---------------------------------------------------------------------------
// conv1: fp32 x [64][3][32][32], binarized w1 [128][3][3][3], +b1, stoch_act
// key0, output packed along channels: [64][32][32][4] words.
// One wave per (n, y, x); lane = co and co+64.
// fp32 accumulation order = (kh outer, kw, ci inner): Eigen/XLA-CPU spatial
// conv packed-K ordering after NHWC+HWIO canonicalization; fma(+-1, x, acc)
// rounds identically to acc +- x.
// ---------------------------------------------------------------------------
__global__ __launch_bounds__(256) void k_conv1(
    const float* __restrict__ x, const float* __restrict__ w1,
    const float* __restrict__ b1, u32 k0, u32 k1, u32* __restrict__ out) {
  int wave = (blockIdx.x * 256 + threadIdx.x) >> 6;
  int lane = threadIdx.x & 63;
  int n = wave >> 10;
  int rem = wave & 1023;
  int y = rem >> 5, xx = rem & 31;

  float xv[27];
#pragma unroll
  for (int ci = 0; ci < 3; ++ci)
#pragma unroll
    for (int dy = -1; dy <= 1; ++dy)
#pragma unroll
      for (int dx = -1; dx <= 1; ++dx) {
        int gy = y + dy, gx = xx + dx;
        float v = 0.0f;
        if ((unsigned)gy < 32u && (unsigned)gx < 32u)
          v = x[((n * 3 + ci) * 32 + gy) * 32 + gx];
        xv[(ci * 3 + (dy + 1)) * 3 + (dx + 1)] = v;
      }

  u64 bm[2];
#pragma unroll
  for (int h = 0; h < 2; ++h) {
    int co = lane + h * 64;
    float acc = 0.0f;
#pragma unroll
    for (int kh = 0; kh < 3; ++kh)
#pragma unroll
      for (int kw = 0; kw < 3; ++kw)
#pragma unroll
        for (int ci = 0; ci < 3; ++ci) {
          int k = (ci * 3 + kh) * 3 + kw;
          float wv = w1[co * 27 + k];
          acc += (wv < 0.0f) ? -xv[k] : xv[k];
        }
    float yv = acc + b1[co];
    u32 j = ((u32)(n * 128 + co) << 10) | (u32)(y << 5) | (u32)xx;
    bm[h] = __ballot(act_neg(yv, k0, k1, j));
  }
  if (lane == 0) {
    u32* o = out + ((n * 32 + y) * 32 + xx) * 4;
    o[0] = (u32)bm[0];
    o[1] = (u32)(bm[0] >> 32);
    o[2] = (u32)bm[1];
    o[3] = (u32)(bm[1] >> 32);
  }
}

// ---------------------------------------------------------------------------
// Binary conv (layers 2..6): in [64][32][32][W] packed, pw [Cout][9][W], +bias,
// stoch_act, out packed [64][32][32][Cout/32]. Block = 64 threads = 32x * 2y,
// grid = (n=64, ypair=16, co-chunk = Cout/32); each thread does 32 cos.
// dot = 32*W*Vtaps - 2 * sum_t popc((a_t ^ w_t) & mask_t)   (exact integer)
// ---------------------------------------------------------------------------
template <int W>
__global__ __launch_bounds__(64) void k_bconv(
    const u32* __restrict__ in, const u32* __restrict__ pw,
    const float* __restrict__ bias, int Cout, u32 k0, u32 k1,
    u32* __restrict__ out) {
  const int lane = threadIdx.x;
  const int xx = lane & 31, yo = lane >> 5;
  const int n = blockIdx.x;
  const int yb = blockIdx.y;
  const int c0 = blockIdx.z * 32;
  const int y = yb * 2 + yo;
  const int WOUT = Cout >> 5;

  __shared__ __align__(16) u32 tile[4][32][W];  // rows yb*2-1 .. yb*2+2

  const int total = 4 * 32 * W;
  for (int idx = lane; idx < total; idx += 64) {
    int wi = idx & (W - 1);
    int xi = (idx / W) & 31;
    int r = idx / (W * 32);
    int gy = yb * 2 - 1 + r;
    if ((unsigned)gy < 32u)
      tile[r][xi][wi] = in[((n * 32 + gy) * 32 + xi) * W + wi];
  }
  __syncthreads();

  u32 mask[9];
  int toff[9];
  int V = 0;
#pragma unroll
  for (int t = 0; t < 9; ++t) {
    int dy = t / 3 - 1, dx = t % 3 - 1;
    int gy = y + dy, gx = xx + dx;
    bool valid = ((unsigned)gy < 32u) && ((unsigned)gx < 32u);
    mask[t] = valid ? 0xffffffffu : 0u;
    V += valid ? 1 : 0;
    int r = yo + dy + 1;
    int xc = gx < 0 ? 0 : (gx > 31 ? 31 : gx);
    toff[t] = (r * 32 + xc) * W;
  }

  const u32* tf = &tile[0][0][0];
  const u32 jbase = ((u32)(n * Cout) << 10) | (u32)(y << 5) | (u32)xx;
  const u32 outoff = (u32)(((n * 32 + y) * 32 + xx) * WOUT);

  u32 packed = 0;
  for (int c = c0; c < c0 + 32; ++c) {
    const u32* wrow = pw + (size_t)c * 9 * W;
    int acc = 0;
#pragma unroll
    for (int t = 0; t < 9; ++t) {
      u32 m = mask[t];
      const u32* a = tf + toff[t];
#pragma unroll
      for (int q = 0; q < W; ++q)
        acc += __popc((a[q] ^ wrow[t * W + q]) & m);
    }
    float yv = (float)(32 * W * V - 2 * acc) + bias[c];
    bool neg = act_neg(yv, k0, k1, jbase + ((u32)c << 10));
    packed |= (neg ? 1u : 0u) << (c & 31);
  }
  out[outoff + (u32)(c0 >> 5)] = packed;
}

// ---------------------------------------------------------------------------
// Repack conv6 output (channel-packed) into FC1 row layout (x-packed):
// f0 row r = n*64 + c_hi, word w: c_lo = w/32, y = w%32, bits = x 0..31,
// channel c = c_hi*8 + c_lo.
// ---------------------------------------------------------------------------
__global__ void k_repack(const u32* __restrict__ a6, u32* __restrict__ f0) {
  int idx = blockIdx.x * blockDim.x + threadIdx.x;
  if (idx >= 4096 * 256) return;
  int w = idx & 255, r = idx >> 8;
  int n = r >> 6, chi = r & 63;
  int clo = w >> 5, yy = w & 31;
  int c = chi * 8 + clo;
  const u32* base = a6 + (size_t)((n * 32 + yy) * 32) * 16 + (c >> 5);
  u32 sh = (u32)(c & 31);
  u32 word = 0;
#pragma unroll
  for (int xp = 0; xp < 32; ++xp)
    word |= ((base[xp * 16] >> sh) & 1u) << xp;
  f0[idx] = word;
}

// ---------------------------------------------------------------------------
// Binary FC (+stoch_act, packed output). Block = 64 threads, 8 rows per block,
// grid = (4096/8, O/o_per_blk). Lane = output o; pack via ballot.
// ---------------------------------------------------------------------------
template <int KW>
__global__ __launch_bounds__(64) void k_fc(
    const u32* __restrict__ in, const u32* __restrict__ pw,
    const float* __restrict__ bias, int O, int o_per_blk, u32 k0, u32 k1,
    u32* __restrict__ out) {
  const int lane = threadIdx.x;
  const int rbase = blockIdx.x * 8;
  const int obase = blockIdx.y * o_per_blk;
  __shared__ __align__(16) u32 rows[8][KW];
  for (int i = lane; i < 8 * KW; i += 64)
    rows[i / KW][i % KW] = in[(size_t)(rbase + i / KW) * KW + (i % KW)];
  __syncthreads();

  const int OW = O >> 5;
  for (int it = 0; it < o_per_blk; it += 64) {
    int o = obase + it + lane;
    const uint4* w4 = (const uint4*)(pw + (size_t)o * KW);
    int acc[8];
#pragma unroll
    for (int rr = 0; rr < 8; ++rr) acc[rr] = 0;
    for (int k4 = 0; k4 < KW / 4; ++k4) {
      uint4 wv = w4[k4];
#pragma unroll
      for (int rr = 0; rr < 8; ++rr) {
        uint4 av = *(const uint4*)&rows[rr][k4 * 4];
        acc[rr] += __popc(av.x ^ wv.x) + __popc(av.y ^ wv.y) +
                   __popc(av.z ^ wv.z) + __popc(av.w ^ wv.w);
      }
    }
    float bo = bias[o];
#pragma unroll
    for (int rr = 0; rr < 8; ++rr) {
      int r = rbase + rr;
      float yv = (float)(KW * 32 - 2 * acc[rr]) + bo;
      bool neg = act_neg(yv, k0, k1, (u32)r * (u32)O + (u32)o);
      u64 b = __ballot(neg);
      if (lane == 0) {
        out[(size_t)r * OW + ((obase + it) >> 5)] = (u32)b;
        out[(size_t)r * OW + ((obase + it) >> 5) + 1] = (u32)(b >> 32);
      }
    }
  }
}

// FC3: [4096][32 words] x [10][32 words] -> fp32 +-1 output [4096][10].
__global__ __launch_bounds__(64) void k_fc3(
    const u32* __restrict__ in, const u32* __restrict__ pw,
    const float* __restrict__ bias, u32 k0, u32 k1,
    float* __restrict__ outp) {
  const int lane = threadIdx.x;
  const int r = blockIdx.x;
  __shared__ u32 row[32];
  if (lane < 32) row[lane] = in[(size_t)r * 32 + lane];
  __syncthreads();
  if (lane < 10) {
    int acc = 0;
#pragma unroll
    for (int k = 0; k < 32; ++k) acc += __popc(row[k] ^ pw[lane * 32 + k]);
    float yv = (float)(1024 - 2 * acc) + bias[lane];
    bool neg = act_neg(yv, k0, k1, (u32)r * 10u + (u32)lane);
    outp[(size_t)r * 10 + lane] = neg ? -1.0f : 1.0f;
  }
}

// ---------------------------------------------------------------------------
extern "C" void kernel_launch(void* const* d_in, const int* in_sizes, int n_in,
                              void* d_out, int out_size, void* d_ws,
                              size_t ws_size, hipStream_t stream) {
  const float* x   = (const float*)d_in[0];
  const float* w1  = (const float*)d_in[1];
  const float* b1  = (const float*)d_in[2];
  const float* w2  = (const float*)d_in[3];
  const float* b2  = (const float*)d_in[4];
  const float* w3  = (const float*)d_in[5];
  const float* b3  = (const float*)d_in[6];
  const float* w4  = (const float*)d_in[7];
  const float* b4  = (const float*)d_in[8];
  const float* w5  = (const float*)d_in[9];
  const float* b5  = (const float*)d_in[10];
  const float* w6  = (const float*)d_in[11];
  const float* b6  = (const float*)d_in[12];
  const float* fw1 = (const float*)d_in[13];
  const float* fb1 = (const float*)d_in[14];
  const float* fw2 = (const float*)d_in[15];
  const float* fb2 = (const float*)d_in[16];
  const float* fw3 = (const float*)d_in[17];
  const float* fb3 = (const float*)d_in[18];

  // 9 subkeys of jax.random.key(42): foldlike split -> TF((0,42),(0,i)).
  u32 K[9][2];
  for (int i = 0; i < 9; ++i) tf2x32(0u, 42u, 0u, (u32)i, K[i][0], K[i][1]);

  char* ws = (char*)d_ws;
  size_t off = 0;
  auto alloc = [&](size_t bytes) -> char* {
    char* p = ws + off;
    off += (bytes + 255) & ~(size_t)255;
    return p;
  };
  u32* pw2  = (u32*)alloc(256u * 9 * 4 * 4);
  u32* pw3  = (u32*)alloc(256u * 9 * 8 * 4);
  u32* pw4  = (u32*)alloc(256u * 9 * 8 * 4);
  u32* pw5  = (u32*)alloc(512u * 9 * 8 * 4);
  u32* pw6  = (u32*)alloc(512u * 9 * 16 * 4);
  u32* pfw1 = (u32*)alloc(1024u * 256 * 4);
  u32* pfw2 = (u32*)alloc(1024u * 32 * 4);
  u32* pfw3 = (u32*)alloc(10u * 32 * 4);
  u32* a1   = (u32*)alloc(64u * 1024 * 4 * 4);
  u32* a2   = (u32*)alloc(64u * 1024 * 8 * 4);
  u32* a3   = (u32*)alloc(64u * 1024 * 8 * 4);
  u32* a4   = (u32*)alloc(64u * 1024 * 8 * 4);
  u32* a5   = (u32*)alloc(64u * 1024 * 16 * 4);
  u32* a6   = (u32*)alloc(64u * 1024 * 16 * 4);
  u32* f0   = (u32*)alloc(4096u * 256 * 4);
  u32* f1   = (u32*)alloc(4096u * 32 * 4);
  u32* f2   = (u32*)alloc(4096u * 32 * 4);
  (void)ws_size;  // requires ~23 MB of workspace

  int t;
  t = 256 * 9 * 4;
  k_pack_convw<<<(t + 255) / 256, 256, 0, stream>>>(w2, pw2, 256, 128);
  t = 256 * 9 * 8;
  k_pack_convw<<<(t + 255) / 256, 256, 0, stream>>>(w3, pw3, 256, 256);
  k_pack_convw<<<(t + 255) / 256, 256, 0, stream>>>(w4, pw4, 256, 256);
  t = 512 * 9 * 8;
  k_pack_convw<<<(t + 255) / 256, 256, 0, stream>>>(w5, pw5, 512, 256);
  t = 512 * 9 * 16;
  k_pack_convw<<<(t + 255) / 256, 256, 0, stream>>>(w6, pw6, 512, 512);
  t = 1024 * 256;
  k_pack_fcw<<<(t + 255) / 256, 256, 0, stream>>>(fw1, pfw1, 1024, 8192);
  t = 1024 * 32;
  k_pack_fcw<<<(t + 255) / 256, 256, 0, stream>>>(fw2, pfw2, 1024, 1024);
  t = 10 * 32;
  k_pack_fcw<<<(t + 255) / 256, 256, 0, stream>>>(fw3, pfw3, 10, 1024);

  k_conv1<<<16384, 256, 0, stream>>>(x, w1, b1, K[0][0], K[0][1], a1);
  k_bconv<4><<<dim3(64, 16, 8), 64, 0, stream>>>(a1, pw2, b2, 256, K[1][0], K[1][1], a2);
  k_bconv<8><<<dim3(64, 16, 8), 64, 0, stream>>>(a2, pw3, b3, 256, K[2][0], K[2][1], a3);
  k_bconv<8><<<dim3(64, 16, 8), 64, 0, stream>>>(a3, pw4, b4, 256, K[3][0], K[3][1], a4);
  k_bconv<8><<<dim3(64, 16, 16), 64, 0, stream>>>(a4, pw5, b5, 512, K[4][0], K[4][1], a5);
  k_bconv<16><<<dim3(64, 16, 16), 64, 0, stream>>>(a5, pw6, b6, 512, K[5][0], K[5][1], a6);
  k_repack<<<(4096 * 256 + 255) / 256, 256, 0, stream>>>(a6, f0);
  k_fc<256><<<dim3(512, 8), 64, 0, stream>>>(f0, pfw1, fb1, 1024, 128, K[6][0], K[6][1], f1);
  k_fc<32><<<dim3(512, 8), 64, 0, stream>>>(f1, pfw2, fb2, 1024, 128, K[7][0], K[7][1], f2);
  k_fc3<<<4096, 64, 0, stream>>>(f2, pfw3, fb3, K[8][0], K[8][1], (float*)d_out);
}

// Round 4
// 3947.178 us; speedup vs baseline: 1.0115x; 1.0115x over previous
//
#include <hip/hip_runtime.h>
#include <stdint.h>

typedef unsigned int u32;
typedef unsigned long long u64;

// ---------------------------------------------------------------------------
// Threefry-2x32, 20 rounds — bit-exact replica of JAX's threefry2x32 primitive.
// ---------------------------------------------------------------------------
__host__ __device__ __forceinline__ void tf2x32(u32 k0, u32 k1, u32 x0, u32 x1,
                                                u32& o0, u32& o1) {
  u32 k2 = k0 ^ k1 ^ 0x1BD11BDAu;
  x0 += k0; x1 += k1;
#define TFR(r) { x0 += x1; x1 = (x1 << (r)) | (x1 >> (32 - (r))); x1 ^= x0; }
  TFR(13) TFR(15) TFR(26) TFR(6)   x0 += k1; x1 += k2 + 1u;
  TFR(17) TFR(29) TFR(16) TFR(24)  x0 += k2; x1 += k0 + 2u;
  TFR(13) TFR(15) TFR(26) TFR(6)   x0 += k0; x1 += k1 + 3u;
  TFR(17) TFR(29) TFR(16) TFR(24)  x0 += k1; x1 += k2 + 4u;
  TFR(13) TFR(15) TFR(26) TFR(6)   x0 += k2; x1 += k0 + 5u;
#undef TFR
  o0 = x0; o1 = x1;
}

// stoch_act: p = clip((y+1)*0.5, 0, 1); u from partitionable random bits of
// flat index j: bits = o0 ^ o1 of TF(key, (0, j)). Returns true if out = -1.
__device__ __forceinline__ bool act_neg(float y, u32 k0, u32 k1, u32 j) {
  u32 o0, o1;
  tf2x32(k0, k1, 0u, j, o0, o1);
  u32 bits = o0 ^ o1;
  float u = __uint_as_float(0x3f800000u | (bits >> 9)) - 1.0f;
  float t = (y + 1.0f) * 0.5f;
  float p = fminf(fmaxf(t, 0.0f), 1.0f);
  return !(u < p);
}

// ---------------------------------------------------------------------------
// Weight packing (bit = 1 iff weight < 0). Conv: [C][Cin][3][3] -> [C][9][W].
// ---------------------------------------------------------------------------
__global__ void k_pack_convw(const float* __restrict__ w, u32* __restrict__ pw,
                             int Cout, int Cin) {
  int Wi = Cin >> 5;
  int idx = blockIdx.x * blockDim.x + threadIdx.x;
  int total = Cout * 9 * Wi;
  if (idx >= total) return;
  int wi = idx % Wi;
  int t = (idx / Wi) % 9;
  int co = idx / (Wi * 9);
  int kh = t / 3, kw = t % 3;
  u32 word = 0;
  for (int b = 0; b < 32; ++b) {
    int ci = wi * 32 + b;
    float v = w[((co * Cin + ci) * 3 + kh) * 3 + kw];
    word |= (v < 0.0f ? 1u : 0u) << b;
  }
  pw[idx] = word;
}

// FC weight pack, transposed for coalesced lane=o loads: pwT[k4][o][j].
__global__ void k_pack_fcwT(const float* __restrict__ w, u32* __restrict__ pwT,
                            int O, int K) {
  int KW = K >> 5;
  int idx = blockIdx.x * blockDim.x + threadIdx.x;
  if (idx >= O * KW) return;
  int kw = idx % KW, o = idx / KW;
  u32 word = 0;
  for (int b = 0; b < 32; ++b)
    word |= (w[(size_t)o * K + kw * 32 + b] < 0.0f ? 1u : 0u) << b;
  int k4 = kw >> 2, j = kw & 3;
  pwT[((size_t)k4 * O + o) * 4 + j] = word;
}

// FC weight pack, row-major (fc3).
__global__ void k_pack_fcw(const float* __restrict__ w, u32* __restrict__ pw,
                           int O, int K) {
  int KW = K >> 5;
  int idx = blockIdx.x * blockDim.x + threadIdx.x;
  if (idx >= O * KW) return;
  int kw = idx % KW, o = idx / KW;
  u32 word = 0;
  for (int b = 0; b < 32; ++b)
    word |= (w[o * K + kw * 32 + b] < 0.0f ? 1u : 0u) << b;
  pw[idx] = word;
}

// ---------------------------------------------------------------------------
// conv1: fp32 x [64][3][32][32], binarized w1, +b1, stoch_act key0,
// output channel-packed [64][32][32][4]. One wave per (n,y,x); lane = co.
// ---------------------------------------------------------------------------
__global__ __launch_bounds__(256) void k_conv1(
    const float* __restrict__ x, const float* __restrict__ w1,
    const float* __restrict__ b1, u32 k0, u32 k1, u32* __restrict__ out) {
  int wave = (blockIdx.x * 256 + threadIdx.x) >> 6;
  int lane = threadIdx.x & 63;
  int n = wave >> 10;
  int rem = wave & 1023;
  int y = rem >> 5, xx = rem & 31;

  float xv[27];
#pragma unroll
  for (int ci = 0; ci < 3; ++ci)
#pragma unroll
    for (int dy = -1; dy <= 1; ++dy)
#pragma unroll
      for (int dx = -1; dx <= 1; ++dx) {
        int gy = y + dy, gx = xx + dx;
        float v = 0.0f;
        if ((unsigned)gy < 32u && (unsigned)gx < 32u)
          v = x[((n * 3 + ci) * 32 + gy) * 32 + gx];
        xv[(ci * 3 + (dy + 1)) * 3 + (dx + 1)] = v;
      }

  u64 bm[2];
#pragma unroll
  for (int h = 0; h < 2; ++h) {
    int co = lane + h * 64;
    float acc = 0.0f;
#pragma unroll
    for (int kh = 0; kh < 3; ++kh)
#pragma unroll
      for (int kw = 0; kw < 3; ++kw)
#pragma unroll
        for (int ci = 0; ci < 3; ++ci) {
          int k = (ci * 3 + kh) * 3 + kw;
          float wv = w1[co * 27 + k];
          acc += (wv < 0.0f) ? -xv[k] : xv[k];
        }
    float yv = acc + b1[co];
    u32 j = ((u32)(n * 128 + co) << 10) | (u32)(y << 5) | (u32)xx;
    bm[h] = __ballot(act_neg(yv, k0, k1, j));
  }
  if (lane == 0) {
    u32* o = out + ((n * 32 + y) * 32 + xx) * 4;
    o[0] = (u32)bm[0];
    o[1] = (u32)(bm[0] >> 32);
    o[2] = (u32)bm[1];
    o[3] = (u32)(bm[1] >> 32);
  }
}

// ---------------------------------------------------------------------------
// Binary conv (layers 2..6) — round-2 proven version. Block = 64 threads =
// 32x * 2y, grid = (n, ypair, co-chunk); each thread does 32 cos.
// dot = 32*W*V - 2 * sum_t popc((a_t ^ w_t) & mask_t)   (exact integer)
// ---------------------------------------------------------------------------
template <int W>
__global__ __launch_bounds__(64) void k_bconv(
    const u32* __restrict__ in, const u32* __restrict__ pw,
    const float* __restrict__ bias, int Cout, u32 k0, u32 k1,
    u32* __restrict__ out) {
  const int lane = threadIdx.x;
  const int xx = lane & 31, yo = lane >> 5;
  const int n = blockIdx.x;
  const int yb = blockIdx.y;
  const int c0 = blockIdx.z * 32;
  const int y = yb * 2 + yo;
  const int WOUT = Cout >> 5;

  __shared__ __align__(16) u32 tile[4][32][W];  // rows yb*2-1 .. yb*2+2

  const int total = 4 * 32 * W;
  for (int idx = lane; idx < total; idx += 64) {
    int wi = idx & (W - 1);
    int xi = (idx / W) & 31;
    int r = idx / (W * 32);
    int gy = yb * 2 - 1 + r;
    if ((unsigned)gy < 32u)
      tile[r][xi][wi] = in[((n * 32 + gy) * 32 + xi) * W + wi];
  }
  __syncthreads();

  u32 mask[9];
  int toff[9];
  int V = 0;
#pragma unroll
  for (int t = 0; t < 9; ++t) {
    int dy = t / 3 - 1, dx = t % 3 - 1;
    int gy = y + dy, gx = xx + dx;
    bool valid = ((unsigned)gy < 32u) && ((unsigned)gx < 32u);
    mask[t] = valid ? 0xffffffffu : 0u;
    V += valid ? 1 : 0;
    int r = yo + dy + 1;
    int xc = gx < 0 ? 0 : (gx > 31 ? 31 : gx);
    toff[t] = (r * 32 + xc) * W;
  }

  const u32* tf = &tile[0][0][0];
  const u32 jbase = ((u32)(n * Cout) << 10) | (u32)(y << 5) | (u32)xx;
  const u32 outoff = (u32)(((n * 32 + y) * 32 + xx) * WOUT);

  u32 packed = 0;
  for (int c = c0; c < c0 + 32; ++c) {
    const u32* wrow = pw + (size_t)c * 9 * W;
    int acc = 0;
#pragma unroll
    for (int t = 0; t < 9; ++t) {
      u32 m = mask[t];
      const u32* a = tf + toff[t];
#pragma unroll
      for (int q = 0; q < W; ++q)
        acc += __popc((a[q] ^ wrow[t * W + q]) & m);
    }
    float yv = (float)(32 * W * V - 2 * acc) + bias[c];
    bool neg = act_neg(yv, k0, k1, jbase + ((u32)c << 10));
    packed |= (neg ? 1u : 0u) << (c & 31);
  }
  out[outoff + (u32)(c0 >> 5)] = packed;
}

// ---------------------------------------------------------------------------
// Repack conv6 output (channel-packed) into FC1 row layout (x-packed).
// ---------------------------------------------------------------------------
__global__ void k_repack(const u32* __restrict__ a6, u32* __restrict__ f0) {
  int idx = blockIdx.x * blockDim.x + threadIdx.x;
  if (idx >= 4096 * 256) return;
  int w = idx & 255, r = idx >> 8;
  int n = r >> 6, chi = r & 63;
  int clo = w >> 5, yy = w & 31;
  int c = chi * 8 + clo;
  const u32* base = a6 + (size_t)((n * 32 + yy) * 32) * 16 + (c >> 5);
  u32 sh = (u32)(c & 31);
  u32 word = 0;
#pragma unroll
  for (int xp = 0; xp < 32; ++xp)
    word |= ((base[xp * 16] >> sh) & 1u) << xp;
  f0[idx] = word;
}

// ---------------------------------------------------------------------------
// Binary FC with transposed weights (under test this round). Block 256 =
// 4 waves; block covers 32 rows (LDS) x 64 outputs; wave w handles 8 rows;
// lane = o (coalesced uint4 weight loads); row words broadcast from LDS.
// ---------------------------------------------------------------------------
template <int KW>
__global__ __launch_bounds__(256, 4) void k_fct(
    const u32* __restrict__ in, const u32* __restrict__ pwT,
    const float* __restrict__ bias, int O, u32 k0, u32 k1,
    u32* __restrict__ out) {
  const int tid = threadIdx.x, lane = tid & 63;
  const int wv = __builtin_amdgcn_readfirstlane(tid >> 6);
  const int rbase = blockIdx.x * 32;
  const int obase = blockIdx.y * 64;
  __shared__ __align__(16) u32 rows[32 * KW];
  for (int i = tid; i < 32 * KW; i += 256)
    rows[i] = in[(size_t)(rbase + i / KW) * KW + (i % KW)];
  __syncthreads();

  const int o = obase + lane;
  const int r0 = wv * 8;
  u32 acc[8];
#pragma unroll
  for (int rr = 0; rr < 8; ++rr) acc[rr] = 0;
  for (int k4 = 0; k4 < KW / 4; ++k4) {
    uint4 w4 = ((const uint4*)pwT)[(size_t)k4 * O + o];
#pragma unroll
    for (int rr = 0; rr < 8; ++rr) {
      uint4 av = *(const uint4*)&rows[(r0 + rr) * KW + k4 * 4];
      acc[rr] += __popc(av.x ^ w4.x) + __popc(av.y ^ w4.y) +
                 __popc(av.z ^ w4.z) + __popc(av.w ^ w4.w);
    }
  }
  const int OW = O >> 5;
  const float bo = bias[o];
#pragma unroll
  for (int rr = 0; rr < 8; ++rr) {
    int r = rbase + r0 + rr;
    float yv = (float)(KW * 32 - 2 * (int)acc[rr]) + bo;
    bool neg = act_neg(yv, k0, k1, (u32)r * (u32)O + (u32)o);
    u64 b = __ballot(neg);
    if (lane == 0) {
      out[(size_t)r * OW + (obase >> 5)] = (u32)b;
      out[(size_t)r * OW + (obase >> 5) + 1] = (u32)(b >> 32);
    }
  }
}

// FC3: [4096][32 words] x [10][32 words] -> fp32 +-1 output [4096][10].
__global__ __launch_bounds__(64) void k_fc3(
    const u32* __restrict__ in, const u32* __restrict__ pw,
    const float* __restrict__ bias, u32 k0, u32 k1,
    float* __restrict__ outp) {
  const int lane = threadIdx.x;
  const int r = blockIdx.x;
  __shared__ u32 row[32];
  if (lane < 32) row[lane] = in[(size_t)r * 32 + lane];
  __syncthreads();
  if (lane < 10) {
    int acc = 0;
#pragma unroll
    for (int k = 0; k < 32; ++k) acc += __popc(row[k] ^ pw[lane * 32 + k]);
    float yv = (float)(1024 - 2 * acc) + bias[lane];
    bool neg = act_neg(yv, k0, k1, (u32)r * 10u + (u32)lane);
    outp[(size_t)r * 10 + lane] = neg ? -1.0f : 1.0f;
  }
}

// ---------------------------------------------------------------------------
extern "C" void kernel_launch(void* const* d_in, const int* in_sizes, int n_in,
                              void* d_out, int out_size, void* d_ws,
                              size_t ws_size, hipStream_t stream) {
  const float* x   = (const float*)d_in[0];
  const float* w1  = (const float*)d_in[1];
  const float* b1  = (const float*)d_in[2];
  const float* w2  = (const float*)d_in[3];
  const float* b2  = (const float*)d_in[4];
  const float* w3  = (const float*)d_in[5];
  const float* b3  = (const float*)d_in[6];
  const float* w4  = (const float*)d_in[7];
  const float* b4  = (const float*)d_in[8];
  const float* w5  = (const float*)d_in[9];
  const float* b5  = (const float*)d_in[10];
  const float* w6  = (const float*)d_in[11];
  const float* b6  = (const float*)d_in[12];
  const float* fw1 = (const float*)d_in[13];
  const float* fb1 = (const float*)d_in[14];
  const float* fw2 = (const float*)d_in[15];
  const float* fb2 = (const float*)d_in[16];
  const float* fw3 = (const float*)d_in[17];
  const float* fb3 = (const float*)d_in[18];

  u32 K[9][2];
  for (int i = 0; i < 9; ++i) tf2x32(0u, 42u, 0u, (u32)i, K[i][0], K[i][1]);

  char* ws = (char*)d_ws;
  size_t off = 0;
  auto alloc = [&](size_t bytes) -> char* {
    char* p = ws + off;
    off += (bytes + 255) & ~(size_t)255;
    return p;
  };
  u32* pw2  = (u32*)alloc(256u * 9 * 4 * 4);
  u32* pw3  = (u32*)alloc(256u * 9 * 8 * 4);
  u32* pw4  = (u32*)alloc(256u * 9 * 8 * 4);
  u32* pw5  = (u32*)alloc(512u * 9 * 8 * 4);
  u32* pw6  = (u32*)alloc(512u * 9 * 16 * 4);
  u32* pfw1 = (u32*)alloc(1024u * 256 * 4);
  u32* pfw2 = (u32*)alloc(1024u * 32 * 4);
  u32* pfw3 = (u32*)alloc(10u * 32 * 4);
  u32* a1   = (u32*)alloc(64u * 1024 * 4 * 4);
  u32* a2   = (u32*)alloc(64u * 1024 * 8 * 4);
  u32* a3   = (u32*)alloc(64u * 1024 * 8 * 4);
  u32* a4   = (u32*)alloc(64u * 1024 * 8 * 4);
  u32* a5   = (u32*)alloc(64u * 1024 * 16 * 4);
  u32* a6   = (u32*)alloc(64u * 1024 * 16 * 4);
  u32* f0   = (u32*)alloc(4096u * 256 * 4);
  u32* f1   = (u32*)alloc(4096u * 32 * 4);
  u32* f2   = (u32*)alloc(4096u * 32 * 4);
  (void)ws_size;  // ~23 MB of workspace

  int t;
  t = 256 * 9 * 4;
  k_pack_convw<<<(t + 255) / 256, 256, 0, stream>>>(w2, pw2, 256, 128);
  t = 256 * 9 * 8;
  k_pack_convw<<<(t + 255) / 256, 256, 0, stream>>>(w3, pw3, 256, 256);
  k_pack_convw<<<(t + 255) / 256, 256, 0, stream>>>(w4, pw4, 256, 256);
  t = 512 * 9 * 8;
  k_pack_convw<<<(t + 255) / 256, 256, 0, stream>>>(w5, pw5, 512, 256);
  t = 512 * 9 * 16;
  k_pack_convw<<<(t + 255) / 256, 256, 0, stream>>>(w6, pw6, 512, 512);
  t = 1024 * 256;
  k_pack_fcwT<<<(t + 255) / 256, 256, 0, stream>>>(fw1, pfw1, 1024, 8192);
  t = 1024 * 32;
  k_pack_fcwT<<<(t + 255) / 256, 256, 0, stream>>>(fw2, pfw2, 1024, 1024);
  t = 10 * 32;
  k_pack_fcw<<<(t + 255) / 256, 256, 0, stream>>>(fw3, pfw3, 10, 1024);

  k_conv1<<<16384, 256, 0, stream>>>(x, w1, b1, K[0][0], K[0][1], a1);
  k_bconv<4><<<dim3(64, 16, 8), 64, 0, stream>>>(a1, pw2, b2, 256,
                                                 K[1][0], K[1][1], a2);
  k_bconv<8><<<dim3(64, 16, 8), 64, 0, stream>>>(a2, pw3, b3, 256,
                                                 K[2][0], K[2][1], a3);
  k_bconv<8><<<dim3(64, 16, 8), 64, 0, stream>>>(a3, pw4, b4, 256,
                                                 K[3][0], K[3][1], a4);
  k_bconv<8><<<dim3(64, 16, 16), 64, 0, stream>>>(a4, pw5, b5, 512,
                                                  K[4][0], K[4][1], a5);
  k_bconv<16><<<dim3(64, 16, 16), 64, 0, stream>>>(a5, pw6, b6, 512,
                                                   K[5][0], K[5][1], a6);
  k_repack<<<(4096 * 256 + 255) / 256, 256, 0, stream>>>(a6, f0);
  k_fct<256><<<dim3(128, 16), 256, 0, stream>>>(f0, pfw1, fb1, 1024,
                                                K[6][0], K[6][1], f1);
  k_fct<32><<<dim3(128, 16), 256, 0, stream>>>(f1, pfw2, fb2, 1024,
                                               K[7][0], K[7][1], f2);
  k_fc3<<<4096, 64, 0, stream>>>(f2, pfw3, fb3, K[8][0], K[8][1],
                                 (float*)d_out);
}